// Round 1
// baseline (76.129 us; speedup 1.0000x reference)
//
#include <hip/hip_runtime.h>

// MixedActivation: x[1000000][48] fp32. Column c: (c%6)<3 -> x*x,
// else PReLU with slope prelu_a[(c%6)-3].
// Pure streaming op: 384 MB HBM traffic, memory-bound. float4 vectorized.

__global__ void MixedActivation_kernel(const float4* __restrict__ x,
                                       const float* __restrict__ a,
                                       float4* __restrict__ out,
                                       int n4) {
    // Three scalar PReLU slopes — uniform loads, L2-cached broadcast.
    const float a0 = a[0], a1 = a[1], a2 = a[2];
    const int stride = gridDim.x * blockDim.x;
    for (int i = blockIdx.x * blockDim.x + threadIdx.x; i < n4; i += stride) {
        float4 v = x[i];
        // Column of first element of this float4. 48%4==0 so the float4
        // never crosses a row boundary; col phase = (4*i) % 48.
        const int base = (i * 4) % 48;
        float in[4] = {v.x, v.y, v.z, v.w};
        float r[4];
#pragma unroll
        for (int k = 0; k < 4; ++k) {
            const int m = (base + k) % 6;           // col % 6
            const float val = in[k];
            const float sq = val * val;
            const float slope = (m == 3) ? a0 : (m == 4) ? a1 : a2;
            const float pr = fmaxf(val, 0.0f) + slope * fminf(val, 0.0f);
            r[k] = (m < 3) ? sq : pr;
        }
        out[i] = make_float4(r[0], r[1], r[2], r[3]);
    }
}

extern "C" void kernel_launch(void* const* d_in, const int* in_sizes, int n_in,
                              void* d_out, int out_size, void* d_ws, size_t ws_size,
                              hipStream_t stream) {
    const float* x = (const float*)d_in[0];
    const float* a = (const float*)d_in[1];
    float* out = (float*)d_out;

    const int n = out_size;        // 48,000,000 elements
    const int n4 = n / 4;          // 12,000,000 float4s (48 % 4 == 0)

    const int block = 256;
    int grid = (n4 + block - 1) / block;
    if (grid > 2048) grid = 2048;  // grid-stride the rest

    MixedActivation_kernel<<<grid, block, 0, stream>>>(
        (const float4*)x, a, (float4*)out, n4);
}

// Round 3
// 69.132 us; speedup vs baseline: 1.1012x; 1.1012x over previous
//
#include <hip/hip_runtime.h>

// MixedActivation: x[1000000][48] fp32. Column c: (c%6)<3 -> x*x,
// else PReLU with slope prelu_a[(c%6)-3].
// Streaming op, 384 MB HBM traffic, memory-bound.
// R3: nontemporal load/store via native clang vector type (HIP_vector_type
// struct is rejected by the builtin) + period-3 pattern arithmetic.

typedef float floatv4 __attribute__((ext_vector_type(4)));

__global__ __launch_bounds__(256)
void MixedActivation_kernel(const floatv4* __restrict__ x,
                            const float* __restrict__ a,
                            floatv4* __restrict__ out,
                            int n4) {
    const float a0 = a[0], a1 = a[1], a2 = a[2];
    const int stride = gridDim.x * blockDim.x;
    for (int i = blockIdx.x * blockDim.x + threadIdx.x; i < n4; i += stride) {
        floatv4 v = __builtin_nontemporal_load(&x[i]);
        // col of elem k in this float4 is (4i + k); pattern key = (4i) % 6.
        // 4i mod 6 depends only on i mod 3: i%3 = 0,1,2 -> 0,4,2.
        const int t = i % 3;
        int b = 4 * t;                 // 0, 4, 8
        if (b >= 6) b -= 6;            // 0, 4, 2
        floatv4 r;
#pragma unroll
        for (int k = 0; k < 4; ++k) {
            int m = b + k;             // (col % 6) before wrap
            if (m >= 6) m -= 6;
            const float val = v[k];
            const float slope = (m == 3) ? a0 : (m == 4) ? a1 : a2;
            const float pr = fmaxf(val, 0.0f) + slope * fminf(val, 0.0f);
            r[k] = (m < 3) ? val * val : pr;
        }
        __builtin_nontemporal_store(r, &out[i]);
    }
}

extern "C" void kernel_launch(void* const* d_in, const int* in_sizes, int n_in,
                              void* d_out, int out_size, void* d_ws, size_t ws_size,
                              hipStream_t stream) {
    const float* x = (const float*)d_in[0];
    const float* a = (const float*)d_in[1];
    float* out = (float*)d_out;

    const int n = out_size;        // 48,000,000 elements
    const int n4 = n / 4;          // 12,000,000 float4s

    const int block = 256;
    int grid = (n4 + block - 1) / block;
    if (grid > 2048) grid = 2048;  // 2048 blocks x 4 waves = 8192 waves
                                   // = 256 CU x 32 wave slots, exact fill

    MixedActivation_kernel<<<grid, block, 0, stream>>>(
        (const floatv4*)x, a, (floatv4*)out, n4);
}